// Round 9
// baseline (1109.663 us; speedup 1.0000x reference)
//
#include <hip/hip_runtime.h>
#include <hip/hip_fp16.h>

#define B_    256
#define CIN   128
#define CH    64
#define NPX   1024   // 32*32
#define NWIN  49
#define TROWS 38     // 32 image rows + 3 halo each side
#define TCOLS 40     // 32 cols + 4 halo each side
#define CELLU 4      // uints per cell = 8 f16 channels = 16 B
#define BUFU  (TROWS * TCOLS * CELLU)   // 6080 uints = 24320 B per buffer
#define NEG_INF_F (-1e30f)

typedef _Float16 h2v __attribute__((ext_vector_type(2)));
typedef __fp16   p2v __attribute__((ext_vector_type(2)));   // cvt_pkrtz result type

#define FDOT2(a, b, c) __builtin_amdgcn_fdot2((a), (b), (c), false)

union CV { p2v p; h2v h; uint u; };
union U4 { int4 v; uint u[4]; h2v h[4]; };

// acc(f32) += f16 half of vu * f16 half of pu — one v_fma_mix_f32.
#define FMIX(acc, vu, vh, pu, ph) do {                                                                              \
    if      ((vh) == 0 && (ph) == 0) asm("v_fma_mix_f32 %0, %1, %2, %0 op_sel:[0,0,0] op_sel_hi:[1,1,0]" : "+v"(acc) : "v"(vu), "v"(pu)); \
    else if ((vh) == 1 && (ph) == 0) asm("v_fma_mix_f32 %0, %1, %2, %0 op_sel:[1,0,0] op_sel_hi:[1,1,0]" : "+v"(acc) : "v"(vu), "v"(pu)); \
    else if ((vh) == 0 && (ph) == 1) asm("v_fma_mix_f32 %0, %1, %2, %0 op_sel:[0,1,0] op_sel_hi:[1,1,0]" : "+v"(acc) : "v"(vu), "v"(pu)); \
    else                             asm("v_fma_mix_f32 %0, %1, %2, %0 op_sel:[1,1,0] op_sel_hi:[1,1,0]" : "+v"(acc) : "v"(vu), "v"(pu)); \
} while (0)

// ---------------------------------------------------------------------------
// Pack W (Ch x Cin) -> pair-interleaved f16 for v_dot2; resolve same_WqWk.
// ---------------------------------------------------------------------------
__global__ __launch_bounds__(256) void wtrans_kernel(
    const float* __restrict__ Wq, const float* __restrict__ Wk,
    const int* __restrict__ same_flag,
    uint* __restrict__ WtPQ, uint* __restrict__ WtPK)
{
    const float* Wsel = (same_flag[0] != 0) ? Wq : Wk;
    for (int idx = threadIdx.x; idx < (CIN / 2) * CH; idx += 256) {
        int i2 = idx >> 6;
        int o  = idx & 63;
        CV a; a.p = __builtin_amdgcn_cvt_pkrtz(Wq[o * CIN + 2 * i2], Wq[o * CIN + 2 * i2 + 1]);
        WtPQ[idx] = a.u;
        CV b2; b2.p = __builtin_amdgcn_cvt_pkrtz(Wsel[o * CIN + 2 * i2], Wsel[o * CIN + 2 * i2 + 1]);
        WtPK[idx] = b2.u;
    }
}

// ---------------------------------------------------------------------------
// Convs (EXACT round-7 structure — 133 us known): y=0 computes BOTH Q and
// K_left from one pass over left; y=1 computes K_right. (256,3) keeps
// 12 waves/CU (latency-bound kernel needs the TLP).
// ---------------------------------------------------------------------------
__global__ __launch_bounds__(256, 3) void conv_kernel(
    const float* __restrict__ left, const float* __restrict__ right,
    const uint* __restrict__ WtPQ, const uint* __restrict__ WtPK,
    const float* __restrict__ bq, const float* __restrict__ bk,
    const int* __restrict__ same_flag,
    uint* __restrict__ dQ, uint* __restrict__ dKL, uint* __restrict__ dKR)
{
    int b  = blockIdx.x >> 2;
    int px = ((blockIdx.x & 3) << 8) + threadIdx.x;
    const float* biasK = (same_flag[0] != 0) ? bq : bk;

    if (blockIdx.y == 0) {
        const float* xb = left + (size_t)b * (CIN * NPX) + px;
        float aq[CH], ak[CH];
#pragma unroll
        for (int o = 0; o < CH; ++o) { aq[o] = bq[o]; ak[o] = biasK[o]; }
#pragma unroll 2
        for (int i2 = 0; i2 < CIN / 2; ++i2) {
            float x0 = xb[(size_t)(2 * i2) << 10];
            float x1 = xb[(size_t)(2 * i2 + 1) << 10];
            CV xp; xp.p = __builtin_amdgcn_cvt_pkrtz(x0, x1);
            const uint* wq = WtPQ + (i2 << 6);
            const uint* wk = WtPK + (i2 << 6);
#pragma unroll
            for (int o = 0; o < CH; ++o) {
                CV wv; wv.u = wq[o];
                aq[o] = FDOT2(xp.h, wv.h, aq[o]);
                CV kv; kv.u = wk[o];
                ak[o] = FDOT2(xp.h, kv.h, ak[o]);
            }
        }
        uint* dbq = dQ  + (size_t)b * ((CH / 2) * NPX) + px;
        uint* dbk = dKL + (size_t)b * ((CH / 2) * NPX) + px;
#pragma unroll
        for (int o2 = 0; o2 < CH / 2; ++o2) {
            CV cq; cq.p = __builtin_amdgcn_cvt_pkrtz(aq[2 * o2], aq[2 * o2 + 1]);
            dbq[(size_t)o2 << 10] = cq.u;
            CV ck; ck.p = __builtin_amdgcn_cvt_pkrtz(ak[2 * o2], ak[2 * o2 + 1]);
            dbk[(size_t)o2 << 10] = ck.u;
        }
    } else {
        const float* xb = right + (size_t)b * (CIN * NPX) + px;
        float ak[CH];
#pragma unroll
        for (int o = 0; o < CH; ++o) ak[o] = biasK[o];
#pragma unroll 4
        for (int i2 = 0; i2 < CIN / 2; ++i2) {
            float x0 = xb[(size_t)(2 * i2) << 10];
            float x1 = xb[(size_t)(2 * i2 + 1) << 10];
            CV xp; xp.p = __builtin_amdgcn_cvt_pkrtz(x0, x1);
            const uint* wk = WtPK + (i2 << 6);
#pragma unroll
            for (int o = 0; o < CH; ++o) {
                CV kv; kv.u = wk[o];
                ak[o] = FDOT2(xp.h, kv.h, ak[o]);
            }
        }
        uint* dbk = dKR + (size_t)b * ((CH / 2) * NPX) + px;
#pragma unroll
        for (int o2 = 0; o2 < CH / 2; ++o2) {
            CV ck; ck.p = __builtin_amdgcn_cvt_pkrtz(ak[2 * o2], ak[2 * o2 + 1]);
            dbk[(size_t)o2 << 10] = ck.u;
        }
    }
}

// staging: 32 rows x 32 cols x 4 ch-pairs per group = 16 uints/thread
#define PFK(g, arr)                                                            \
    _Pragma("unroll") for (int i = 0; i < 16; ++i)                             \
        arr[i] = Kb[((size_t)(((g) << 2) + c2) << 10) + ((rr + 2 * i) << 5) + w];
#define WRK(bp, arr)                                                           \
    _Pragma("unroll") for (int i = 0; i < 16; ++i)                             \
        (bp)[((3 + rr + 2 * i) * TCOLS + (w + 4)) * CELLU + c2] = arr[i];

// ---------------------------------------------------------------------------
// One 2-px score pass (rows hA = 4*rq+P0 and hA+1): stages all 8 K groups
// (double-buffered, register-prefetched), shared taps, masked softmax, packs
// weights into phA/phB (f16 pairs). Only one sc0+sc1 pair live at a time.
// ---------------------------------------------------------------------------
template<int P0>
__device__ __forceinline__ void score_pass2(
    const uint* __restrict__ Kb, const uint* __restrict__ Qb, uint* buf,
    int rq, int w, int c2, int rr, uint* phA, uint* phB)
{
    const int hA    = (rq << 2) + P0;
    const int qoffA = (hA << 5) + w;

    float sc0[NWIN], sc1[NWIN];
#pragma unroll
    for (int i = 0; i < NWIN; ++i) { sc0[i] = 0.f; sc1[i] = 0.f; }

    uint pfa[16], pfb[16];
    PFK(0, pfa); PFK(1, pfb);
#pragma unroll 1
    for (int gp = 0; gp < 4; ++gp) {
        __syncthreads();                 // prior compute / zero-fill done
        WRK(buf, pfa); WRK(buf + BUFU, pfb);
        if (gp < 3) { PFK(2 * gp + 2, pfa); PFK(2 * gp + 3, pfb); }
        __syncthreads();                 // staged data visible

#pragma unroll
        for (int half = 0; half < 2; ++half) {
            const uint* bp = buf + half * BUFU;
            const int g = 2 * gp + half;
            CV qa[4], qc[4];
#pragma unroll
            for (int j = 0; j < 4; ++j) {
                qa[j].u = Qb[((size_t)((g << 2) + j) << 10) + qoffA];
                qc[j].u = Qb[((size_t)((g << 2) + j) << 10) + qoffA + 32];
            }
#pragma unroll
            for (int dh = 0; dh < 8; ++dh) {
                int cu0 = ((hA + dh) * TCOLS + (w + 1)) * CELLU;
#pragma unroll
                for (int dw = 0; dw < 7; ++dw) {
                    U4 kk; kk.v = *(const int4*)(bp + cu0 + dw * CELLU);
                    if (dh < 7) {
                        float s = sc0[dh * 7 + dw];
#pragma unroll
                        for (int j = 0; j < 4; ++j) s = FDOT2(kk.h[j], qa[j].h, s);
                        sc0[dh * 7 + dw] = s;
                    }
                    if (dh >= 1) {
                        float s = sc1[(dh - 1) * 7 + dw];
#pragma unroll
                        for (int j = 0; j < 4; ++j) s = FDOT2(kk.h[j], qc[j].h, s);
                        sc1[(dh - 1) * 7 + dw] = s;
                    }
                }
            }
        }
    }

    // masked softmax px A
    {
        float m = NEG_INF_F;
#pragma unroll
        for (int dh = 0; dh < 7; ++dh)
#pragma unroll
            for (int dw = 0; dw < 7; ++dw) {
                int i = dh * 7 + dw;
                bool vld = ((unsigned)(hA + dh - 3) < 32u) && ((unsigned)(w + dw - 3) < 32u);
                sc0[i] = vld ? sc0[i] : NEG_INF_F;
                m = fmaxf(m, sc0[i]);
            }
        float ssum = 0.f;
#pragma unroll
        for (int i = 0; i < NWIN; ++i) { sc0[i] = __expf(sc0[i] - m); ssum += sc0[i]; }
        float inv = 1.f / ssum;
#pragma unroll
        for (int j = 0; j < 24; ++j) {
            CV cv; cv.p = __builtin_amdgcn_cvt_pkrtz(sc0[2 * j] * inv, sc0[2 * j + 1] * inv);
            phA[j] = cv.u;
        }
        CV cv; cv.p = __builtin_amdgcn_cvt_pkrtz(sc0[48] * inv, 0.f);
        phA[24] = cv.u;
    }
    // masked softmax px B (row hA+1)
    {
        float m = NEG_INF_F;
#pragma unroll
        for (int dh = 0; dh < 7; ++dh)
#pragma unroll
            for (int dw = 0; dw < 7; ++dw) {
                int i = dh * 7 + dw;
                bool vld = ((unsigned)(hA + 1 + dh - 3) < 32u) && ((unsigned)(w + dw - 3) < 32u);
                sc1[i] = vld ? sc1[i] : NEG_INF_F;
                m = fmaxf(m, sc1[i]);
            }
        float ssum = 0.f;
#pragma unroll
        for (int i = 0; i < NWIN; ++i) { sc1[i] = __expf(sc1[i] - m); ssum += sc1[i]; }
        float inv = 1.f / ssum;
#pragma unroll
        for (int j = 0; j < 24; ++j) {
            CV cv; cv.p = __builtin_amdgcn_cvt_pkrtz(sc1[2 * j] * inv, sc1[2 * j + 1] * inv);
            phB[j] = cv.u;
        }
        CV cv; cv.p = __builtin_amdgcn_cvt_pkrtz(sc1[48] * inv, 0.f);
        phB[24] = cv.u;
    }
}

// ---------------------------------------------------------------------------
// Fused local attention, 4 vertical px per thread, whole 32x32 image per
// block (256 blocks/side = exactly 2 blocks/CU). Phase A: two 2-px score
// passes. Phase C: one tap read serves up to FOUR pixels (70 reads per
// 196 px-taps -> 0.625x LDS bytes). waves_per_eu(2,2): 256-VGPR budget.
// ---------------------------------------------------------------------------
__global__ __launch_bounds__(256) __attribute__((amdgpu_waves_per_eu(2, 2)))
void attend2_kernel(
    const uint* __restrict__ Q, const uint* __restrict__ KR,
    const uint* __restrict__ KL,
    const float* __restrict__ right, const float* __restrict__ left,
    float* __restrict__ out, const int* __restrict__ self_flag)
{
    __shared__ __align__(16) uint buf[2 * BUFU];   // 48640 B

    int side = blockIdx.y;            // 0: right-attend, 1: left-attend
    int b    = blockIdx.x;
    int t    = threadIdx.x;
    int w    = t & 31;
    int rq   = t >> 5;                // 0..7 -> rows 4rq..4rq+3
    int cb   = side ? 0 : CIN;

    const uint*  K = side ? KL : KR;
    const float* V = side ? left : right;

    if (side == 1 && self_flag[0] == 0) {
        const float* s = left + (size_t)b * (CIN * NPX) + ((rq << 2) << 5) + w;
        float* d = out + (size_t)b * (2 * CIN * NPX) + ((rq << 2) << 5) + w;
        for (int c = 0; c < CIN; ++c)
#pragma unroll
            for (int p = 0; p < 4; ++p)
                d[((size_t)c << 10) + (p << 5)] = s[((size_t)c << 10) + (p << 5)];
        return;
    }

    // ---- zero both buffers once (halo stays 0 through A and C) ----
#pragma unroll
    for (int i = 0; i < 12; ++i) {
        int idx = t + (i << 8);
        if (idx < 2 * BUFU / 4) ((int4*)buf)[idx] = int4{0, 0, 0, 0};
    }

    int c2 = (t >> 5) & 3;            // staging channel-pair within group
    int rr = t >> 7;                  // staging row parity (0/1)

    const uint* Kb = K + (size_t)b * ((CH / 2) * NPX);
    const uint* Qb = Q + (size_t)b * ((CH / 2) * NPX);

    // ---- Phase A: two 2-px passes ----
    uint ph0[25], ph1[25], ph2[25], ph3[25];
    score_pass2<0>(Kb, Qb, buf, rq, w, c2, rr, ph0, ph1);
    score_pass2<2>(Kb, Qb, buf, rq, w, c2, rr, ph2, ph3);

    // ---- Phase C: 16 groups of 8 ch; taps shared across 4 px ----
    const float* Vb = V + (size_t)b * (CIN * NPX);
    float* ob = out + (size_t)b * (2 * CIN * NPX) + ((size_t)cb << 10) + ((rq << 2) << 5) + w;

    float pv0[16], pv1[16];
#define PFV(vg) {                                                              \
    const float* va = Vb + ((size_t)(((((vg) << 2) + c2)) * 2) << 10);         \
    const float* vc = va + NPX;                                                \
    _Pragma("unroll") for (int i = 0; i < 16; ++i) {                           \
        int gi = ((rr + 2 * i) << 5) + w;                                      \
        pv0[i] = va[gi]; pv1[i] = vc[gi];                                      \
    } }

    PFV(0);
#pragma unroll 1
    for (int vg = 0; vg < 16; ++vg) {
        __syncthreads();                     // prior reads of buf done
#pragma unroll
        for (int i = 0; i < 16; ++i) {
            CV cv; cv.p = __builtin_amdgcn_cvt_pkrtz(pv0[i], pv1[i]);
            buf[((3 + rr + 2 * i) * TCOLS + (w + 4)) * CELLU + c2] = cv.u;
        }
        if (vg < 15) PFV(vg + 1);
        __syncthreads();                     // staged data visible

        float a0[8], a1[8], a2[8], a3[8];
#pragma unroll
        for (int c = 0; c < 8; ++c) { a0[c] = 0.f; a1[c] = 0.f; a2[c] = 0.f; a3[c] = 0.f; }

#pragma unroll
        for (int dh = 0; dh < 10; ++dh) {
            int cu0 = (((rq << 2) + dh) * TCOLS + (w + 1)) * CELLU;
#pragma unroll
            for (int dw = 0; dw < 7; ++dw) {
                U4 kk; kk.v = *(const int4*)(buf + cu0 + dw * CELLU);
#define PVACC(p, AP, PHP)                                                      \
                if (dh >= (p) && dh <= (p) + 6) {                              \
                    int tp = (dh - (p)) * 7 + dw;                              \
                    _Pragma("unroll") for (int c = 0; c < 8; ++c)              \
                        FMIX(AP[c], kk.u[c >> 1], (c & 1), PHP[tp >> 1], (tp & 1)); \
                }
                PVACC(0, a0, ph0)
                PVACC(1, a1, ph1)
                PVACC(2, a2, ph2)
                PVACC(3, a3, ph3)
#undef PVACC
            }
        }
#pragma unroll
        for (int c = 0; c < 8; ++c) {
            size_t co = (size_t)((vg << 3) + c) << 10;
            ob[co]      = a0[c];
            ob[co + 32] = a1[c];
            ob[co + 64] = a2[c];
            ob[co + 96] = a3[c];
        }
    }
}

// ---------------------------------------------------------------------------
// 3 launches: wtrans -> conv (2048 blocks) -> attend2 (512 blocks).
// ws: 3 x 32 MiB pair-packed f16 (Q, K_left, K_right) + 2 packed W = 96.03 MiB.
// ---------------------------------------------------------------------------
extern "C" void kernel_launch(void* const* d_in, const int* in_sizes, int n_in,
                              void* d_out, int out_size, void* d_ws, size_t ws_size,
                              hipStream_t stream)
{
    (void)in_sizes; (void)n_in; (void)out_size; (void)ws_size;

    const float* left  = (const float*)d_in[0];
    const float* right = (const float*)d_in[1];
    const float* Wq    = (const float*)d_in[2];
    const float* bq    = (const float*)d_in[3];
    const float* Wk    = (const float*)d_in[4];
    const float* bk    = (const float*)d_in[5];
    const int* self_flag = (const int*)d_in[7];
    const int* same_flag = (const int*)d_in[8];

    uint* wsQ  = (uint*)d_ws;                              // 32 MiB
    uint* wsKL = wsQ  + (size_t)B_ * (CH / 2) * NPX;       // 32 MiB
    uint* wsKR = wsKL + (size_t)B_ * (CH / 2) * NPX;       // 32 MiB
    uint* WtPQ = wsKR + (size_t)B_ * (CH / 2) * NPX;       // 4096 uints
    uint* WtPK = WtPQ + (CIN / 2) * CH;

    float* out = (float*)d_out;

    wtrans_kernel<<<1, 256, 0, stream>>>(Wq, Wk, same_flag, WtPQ, WtPK);

    conv_kernel<<<dim3(B_ * 4, 2), 256, 0, stream>>>(
        left, right, WtPQ, WtPK, bq, bk, same_flag, wsQ, wsKL, wsKR);

    attend2_kernel<<<dim3(B_, 2), 256, 0, stream>>>(
        wsQ, wsKR, wsKL, right, left, out, self_flag);
}

// Round 10
// 322.804 us; speedup vs baseline: 3.4376x; 3.4376x over previous
//
#include <hip/hip_runtime.h>
#include <hip/hip_fp16.h>

#define B_    256
#define CIN   128
#define CH    64
#define NPX   1024   // 32*32
#define NWIN  49
#define TROWS 22     // 16 tile rows + 3 halo each side
#define TCOLS 40     // 32 cols + 4 halo each side
#define CELLU 4      // uints per cell = 8 f16 channels = 16 B (benign 8-way banking)
#define BUFU  (TROWS * TCOLS * CELLU)   // 3520 uints = 14080 B per buffer
#define NEG_INF_F (-1e30f)

typedef _Float16 h2v __attribute__((ext_vector_type(2)));
typedef __fp16   p2v __attribute__((ext_vector_type(2)));   // cvt_pkrtz result type

#define FDOT2(a, b, c) __builtin_amdgcn_fdot2((a), (b), (c), false)

union CV { p2v p; h2v h; uint u; };
union U4 { int4 v; uint u[4]; h2v h[4]; };

// acc(f32) += f16 half of vu * f16 half of pu — one v_fma_mix_f32.
#define FMIX(acc, vu, vh, pu, ph) do {                                                                              \
    if      ((vh) == 0 && (ph) == 0) asm("v_fma_mix_f32 %0, %1, %2, %0 op_sel:[0,0,0] op_sel_hi:[1,1,0]" : "+v"(acc) : "v"(vu), "v"(pu)); \
    else if ((vh) == 1 && (ph) == 0) asm("v_fma_mix_f32 %0, %1, %2, %0 op_sel:[1,0,0] op_sel_hi:[1,1,0]" : "+v"(acc) : "v"(vu), "v"(pu)); \
    else if ((vh) == 0 && (ph) == 1) asm("v_fma_mix_f32 %0, %1, %2, %0 op_sel:[0,1,0] op_sel_hi:[1,1,0]" : "+v"(acc) : "v"(vu), "v"(pu)); \
    else                             asm("v_fma_mix_f32 %0, %1, %2, %0 op_sel:[1,1,0] op_sel_hi:[1,1,0]" : "+v"(acc) : "v"(vu), "v"(pu)); \
} while (0)

// ---------------------------------------------------------------------------
// Pack W (Ch x Cin) -> pair-interleaved f16 for v_dot2; resolve same_WqWk.
// ---------------------------------------------------------------------------
__global__ __launch_bounds__(256) void wtrans_kernel(
    const float* __restrict__ Wq, const float* __restrict__ Wk,
    const int* __restrict__ same_flag,
    uint* __restrict__ WtPQ, uint* __restrict__ WtPK)
{
    const float* Wsel = (same_flag[0] != 0) ? Wq : Wk;
    for (int idx = threadIdx.x; idx < (CIN / 2) * CH; idx += 256) {
        int i2 = idx >> 6;
        int o  = idx & 63;
        CV a; a.p = __builtin_amdgcn_cvt_pkrtz(Wq[o * CIN + 2 * i2], Wq[o * CIN + 2 * i2 + 1]);
        WtPQ[idx] = a.u;
        CV b2; b2.p = __builtin_amdgcn_cvt_pkrtz(Wsel[o * CIN + 2 * i2], Wsel[o * CIN + 2 * i2 + 1]);
        WtPK[idx] = b2.u;
    }
}

// ---------------------------------------------------------------------------
// ROUND-6 conv3 (measured ~108 us): three separate 1x1 convs
// (blockIdx.y = 0:Q(left) 1:K(left) 2:K(right)), v_dot2_f32_f16,
// (256,4) -> VGPR ~64, high TLP for the latency-bound strided loads.
// ---------------------------------------------------------------------------
__global__ __launch_bounds__(256, 4) void conv3_kernel(
    const float* __restrict__ left, const float* __restrict__ right,
    const uint* __restrict__ WtPQ, const uint* __restrict__ WtPK,
    const float* __restrict__ bq, const float* __restrict__ bk,
    const int* __restrict__ same_flag,
    uint* __restrict__ dQ, uint* __restrict__ dKL, uint* __restrict__ dKR)
{
    int which = blockIdx.y;
    const float* x    = (which == 2) ? right : left;
    const uint*  Wt   = (which == 0) ? WtPQ : WtPK;
    const float* bias = (which == 0 || same_flag[0] != 0) ? bq : bk;
    uint* dst         = (which == 0) ? dQ : ((which == 1) ? dKL : dKR);

    int b  = blockIdx.x >> 2;
    int px = ((blockIdx.x & 3) << 8) + threadIdx.x;
    const float* xb = x + (size_t)b * (CIN * NPX) + px;

    float acc[CH];
#pragma unroll
    for (int o = 0; o < CH; ++o) acc[o] = bias[o];

#pragma unroll 4
    for (int i2 = 0; i2 < CIN / 2; ++i2) {
        float x0 = xb[(size_t)(2 * i2) << 10];
        float x1 = xb[(size_t)(2 * i2 + 1) << 10];
        CV xp; xp.p = __builtin_amdgcn_cvt_pkrtz(x0, x1);
        const uint* wrow = Wt + (i2 << 6);
#pragma unroll
        for (int o = 0; o < CH; ++o) {
            CV wv; wv.u = wrow[o];
            acc[o] = FDOT2(xp.h, wv.h, acc[o]);
        }
    }

    uint* db = dst + (size_t)b * ((CH / 2) * NPX) + px;
#pragma unroll
    for (int o2 = 0; o2 < CH / 2; ++o2) {
        CV cv; cv.p = __builtin_amdgcn_cvt_pkrtz(acc[2 * o2], acc[2 * o2 + 1]);
        db[(size_t)o2 << 10] = cv.u;
    }
}

// ---------------------------------------------------------------------------
// ROUND-7 attend2 structure + waves_per_eu(2,2) (measured ~170 us in round 8).
// 16-row tile, 2 vertical px/thread, shared taps in both phases; dbuf +
// register-prefetched staging; 256-VGPR budget pins sc0+sc1+ph in VGPRs.
// ---------------------------------------------------------------------------
__global__ __launch_bounds__(256) __attribute__((amdgpu_waves_per_eu(2, 2)))
void attend2_kernel(
    const uint* __restrict__ Q, const uint* __restrict__ KR,
    const uint* __restrict__ KL,
    const float* __restrict__ right, const float* __restrict__ left,
    float* __restrict__ out, const int* __restrict__ self_flag)
{
    __shared__ __align__(16) uint buf[2 * BUFU];   // 28160 B

    int side = blockIdx.y;            // 0: right-attend, 1: left-attend
    int b    = blockIdx.x >> 1;
    int h0   = (blockIdx.x & 1) << 4;
    int t    = threadIdx.x;
    int w    = t & 31;
    int r2   = (t >> 5) << 1;         // 0,2,..,14
    int h    = h0 + r2;               // rows h and h+1
    int qoff = (h << 5) + w;
    int cb   = side ? 0 : CIN;

    const uint*  K = side ? KL : KR;
    const float* V = side ? left : right;

    if (side == 1 && self_flag[0] == 0) {
        const float* s = left + (size_t)b * (CIN * NPX) + qoff;
        float* d = out + (size_t)b * (2 * CIN * NPX) + qoff;
        for (int c = 0; c < CIN; ++c) {
            d[(size_t)c << 10] = s[(size_t)c << 10];
            d[((size_t)c << 10) + 32] = s[((size_t)c << 10) + 32];
        }
        return;
    }

    // ---- zero both buffers once (borders stay 0 through A and C) ----
#pragma unroll
    for (int i = 0; i < 7; ++i) {
        int idx = t + (i << 8);
        if (idx < 2 * BUFU / 4) ((int4*)buf)[idx] = int4{0, 0, 0, 0};
    }

    int rowlo = (h0 == 0) ? 0 : h0 - 3;   // first valid global row (19 staged)
    int rowof = (h0 == 0) ? 3 : 0;        // its LDS row
    int c2    = (t >> 5) & 3;             // staging channel-pair within group
    int rr    = t >> 7;                   // staging row parity

    const uint* Kb = K + (size_t)b * ((CH / 2) * NPX);
    const uint* Qb = Q + (size_t)b * ((CH / 2) * NPX);

    float sc0[NWIN], sc1[NWIN];
#pragma unroll
    for (int i = 0; i < NWIN; ++i) { sc0[i] = 0.f; sc1[i] = 0.f; }

#define ROWS_OK(i) (rr + 2 * (i) < 19)
#define PFK(g, arr)                                                            \
    _Pragma("unroll") for (int i = 0; i < 10; ++i) if (ROWS_OK(i))             \
        arr[i] = Kb[((size_t)((((g) << 2) + c2)) << 10) + ((rowlo + rr + 2 * i) << 5) + w];
#define WRK(bp, arr)                                                           \
    _Pragma("unroll") for (int i = 0; i < 10; ++i) if (ROWS_OK(i))             \
        (bp)[((rowof + rr + 2 * i) * TCOLS + (w + 4)) * CELLU + c2] = arr[i];

#define COMPA(bp, g) {                                                         \
    CV qa[4], qc[4];                                                           \
    _Pragma("unroll") for (int j = 0; j < 4; ++j) {                            \
        qa[j].u = Qb[((size_t)(((g) << 2) + j) << 10) + qoff];                 \
        qc[j].u = Qb[((size_t)(((g) << 2) + j) << 10) + qoff + 32];            \
    }                                                                          \
    _Pragma("unroll") for (int dh = 0; dh < 8; ++dh) {                         \
        int cu0 = ((r2 + dh) * TCOLS + (w + 1)) * CELLU;                       \
        _Pragma("unroll") for (int dw = 0; dw < 7; ++dw) {                     \
            U4 kk; kk.v = *(const int4*)((bp) + cu0 + dw * CELLU);             \
            if (dh < 7) {                                                      \
                float s = sc0[dh * 7 + dw];                                    \
                _Pragma("unroll") for (int j = 0; j < 4; ++j)                  \
                    s = FDOT2(kk.h[j], qa[j].h, s);                            \
                sc0[dh * 7 + dw] = s;                                          \
            }                                                                  \
            if (dh >= 1) {                                                     \
                float s = sc1[(dh - 1) * 7 + dw];                              \
                _Pragma("unroll") for (int j = 0; j < 4; ++j)                  \
                    s = FDOT2(kk.h[j], qc[j].h, s);                            \
                sc1[(dh - 1) * 7 + dw] = s;                                    \
            }                                                                  \
        }                                                                      \
    } }

    // ---- Phase A: 8 groups of 8 ch, processed in dbuf pairs ----
    {
        uint pfa[10], pfb[10];
        PFK(0, pfa); PFK(1, pfb);
#pragma unroll 1
        for (int gp = 0; gp < 4; ++gp) {
            __syncthreads();                 // prior compute / zero-fill done
            WRK(buf, pfa); WRK(buf + BUFU, pfb);
            if (gp < 3) { PFK(2 * gp + 2, pfa); PFK(2 * gp + 3, pfb); }
            __syncthreads();                 // staged data visible
            COMPA(buf, 2 * gp);
            COMPA(buf + BUFU, 2 * gp + 1);
        }
    }

    // ---- masked softmax per pixel; weights packed to f16 pairs ----
    uint ph0[25], ph1[25];
    {
        float m = NEG_INF_F;
#pragma unroll
        for (int dh = 0; dh < 7; ++dh)
#pragma unroll
            for (int dw = 0; dw < 7; ++dw) {
                int i = dh * 7 + dw;
                bool vld = ((unsigned)(h + dh - 3) < 32u) && ((unsigned)(w + dw - 3) < 32u);
                sc0[i] = vld ? sc0[i] : NEG_INF_F;
                m = fmaxf(m, sc0[i]);
            }
        float ssum = 0.f;
#pragma unroll
        for (int i = 0; i < NWIN; ++i) { sc0[i] = __expf(sc0[i] - m); ssum += sc0[i]; }
        float inv = 1.f / ssum;
#pragma unroll
        for (int j = 0; j < 24; ++j) {
            CV cv; cv.p = __builtin_amdgcn_cvt_pkrtz(sc0[2 * j] * inv, sc0[2 * j + 1] * inv);
            ph0[j] = cv.u;
        }
        CV cv; cv.p = __builtin_amdgcn_cvt_pkrtz(sc0[48] * inv, 0.f);
        ph0[24] = cv.u;
    }
    {
        float m = NEG_INF_F;
#pragma unroll
        for (int dh = 0; dh < 7; ++dh)
#pragma unroll
            for (int dw = 0; dw < 7; ++dw) {
                int i = dh * 7 + dw;
                bool vld = ((unsigned)(h + 1 + dh - 3) < 32u) && ((unsigned)(w + dw - 3) < 32u);
                sc1[i] = vld ? sc1[i] : NEG_INF_F;
                m = fmaxf(m, sc1[i]);
            }
        float ssum = 0.f;
#pragma unroll
        for (int i = 0; i < NWIN; ++i) { sc1[i] = __expf(sc1[i] - m); ssum += sc1[i]; }
        float inv = 1.f / ssum;
#pragma unroll
        for (int j = 0; j < 24; ++j) {
            CV cv; cv.p = __builtin_amdgcn_cvt_pkrtz(sc1[2 * j] * inv, sc1[2 * j + 1] * inv);
            ph1[j] = cv.u;
        }
        CV cv; cv.p = __builtin_amdgcn_cvt_pkrtz(sc1[48] * inv, 0.f);
        ph1[24] = cv.u;
    }

    // ---- Phase C: 16 groups of 8 ch, prefetched f32 V, shared taps ----
    const float* Vb = V + (size_t)b * (CIN * NPX);
    float* ob = out + (size_t)b * (2 * CIN * NPX) + ((size_t)cb << 10) + qoff;

    float pv0[10], pv1[10];
#define PFV(vg) {                                                              \
    const float* va = Vb + ((size_t)((((vg) << 2) + c2) * 2) << 10);           \
    const float* vc = va + NPX;                                                \
    _Pragma("unroll") for (int i = 0; i < 10; ++i) if (ROWS_OK(i)) {           \
        int gi = ((rowlo + rr + 2 * i) << 5) + w;                              \
        pv0[i] = va[gi]; pv1[i] = vc[gi];                                      \
    } }

    PFV(0);
#pragma unroll 1
    for (int vg = 0; vg < 16; ++vg) {
        __syncthreads();                     // prior reads of buf done
#pragma unroll
        for (int i = 0; i < 10; ++i) if (ROWS_OK(i)) {
            CV cv; cv.p = __builtin_amdgcn_cvt_pkrtz(pv0[i], pv1[i]);
            buf[((rowof + rr + 2 * i) * TCOLS + (w + 4)) * CELLU + c2] = cv.u;
        }
        if (vg < 15) PFV(vg + 1);
        __syncthreads();                     // staged data visible

        float a0[8], a1[8];
#pragma unroll
        for (int c = 0; c < 8; ++c) { a0[c] = 0.f; a1[c] = 0.f; }

#pragma unroll
        for (int dh = 0; dh < 8; ++dh) {
            int cu0 = ((r2 + dh) * TCOLS + (w + 1)) * CELLU;
#pragma unroll
            for (int dw = 0; dw < 7; ++dw) {
                U4 kk; kk.v = *(const int4*)(buf + cu0 + dw * CELLU);
                if (dh < 7) {
                    int tp = dh * 7 + dw;
#pragma unroll
                    for (int c = 0; c < 8; ++c)
                        FMIX(a0[c], kk.u[c >> 1], (c & 1), ph0[tp >> 1], (tp & 1));
                }
                if (dh >= 1) {
                    int tp = (dh - 1) * 7 + dw;
#pragma unroll
                    for (int c = 0; c < 8; ++c)
                        FMIX(a1[c], kk.u[c >> 1], (c & 1), ph1[tp >> 1], (tp & 1));
                }
            }
        }
#pragma unroll
        for (int c = 0; c < 8; ++c) {
            ob[((size_t)((vg << 3) + c)) << 10] = a0[c];
            ob[(((size_t)((vg << 3) + c)) << 10) + 32] = a1[c];
        }
    }
}

// ---------------------------------------------------------------------------
// 3 launches: wtrans -> conv3 (3072 blocks) -> attend2 (1024 blocks).
// ws: 3 x 32 MiB pair-packed f16 (Q, K_left, K_right) + 2 packed W = 96.03 MiB.
// ---------------------------------------------------------------------------
extern "C" void kernel_launch(void* const* d_in, const int* in_sizes, int n_in,
                              void* d_out, int out_size, void* d_ws, size_t ws_size,
                              hipStream_t stream)
{
    (void)in_sizes; (void)n_in; (void)out_size; (void)ws_size;

    const float* left  = (const float*)d_in[0];
    const float* right = (const float*)d_in[1];
    const float* Wq    = (const float*)d_in[2];
    const float* bq    = (const float*)d_in[3];
    const float* Wk    = (const float*)d_in[4];
    const float* bk    = (const float*)d_in[5];
    const int* self_flag = (const int*)d_in[7];
    const int* same_flag = (const int*)d_in[8];

    uint* wsQ  = (uint*)d_ws;                              // 32 MiB
    uint* wsKL = wsQ  + (size_t)B_ * (CH / 2) * NPX;       // 32 MiB
    uint* wsKR = wsKL + (size_t)B_ * (CH / 2) * NPX;       // 32 MiB
    uint* WtPQ = wsKR + (size_t)B_ * (CH / 2) * NPX;       // 4096 uints
    uint* WtPK = WtPQ + (CIN / 2) * CH;

    float* out = (float*)d_out;

    wtrans_kernel<<<1, 256, 0, stream>>>(Wq, Wk, same_flag, WtPQ, WtPK);

    conv3_kernel<<<dim3(B_ * 4, 3), 256, 0, stream>>>(
        left, right, WtPQ, WtPK, bq, bk, same_flag, wsQ, wsKL, wsKR);

    attend2_kernel<<<dim3(B_ * 2, 2), 256, 0, stream>>>(
        wsQ, wsKR, wsKL, right, left, out, self_flag);
}

// Round 11
// 298.770 us; speedup vs baseline: 3.7141x; 1.0804x over previous
//
#include <hip/hip_runtime.h>
#include <hip/hip_fp16.h>

#define B_    256
#define CIN   128
#define CH    64
#define NPX   1024   // 32*32
#define NWIN  49
#define TROWS 22     // 16 tile rows + 3 halo each side
#define TCOLS 40     // 32 cols + 4 halo each side
#define CELLU 4      // uints per cell = 8 f16 channels = 16 B (benign 8-way banking)
#define BUFU  (TROWS * TCOLS * CELLU)   // 3520 uints = 14080 B per buffer
#define NEG_INF_F (-1e30f)

typedef _Float16 h2v __attribute__((ext_vector_type(2)));
typedef __fp16   p2v __attribute__((ext_vector_type(2)));   // cvt_pkrtz result type

#define FDOT2(a, b, c) __builtin_amdgcn_fdot2((a), (b), (c), false)

union CV { p2v p; h2v h; uint u; };
union U4 { int4 v; uint u[4]; h2v h[4]; };

// acc(f32) += f16 half of vu * f16 half of pu — one v_fma_mix_f32.
#define FMIX(acc, vu, vh, pu, ph) do {                                                                              \
    if      ((vh) == 0 && (ph) == 0) asm("v_fma_mix_f32 %0, %1, %2, %0 op_sel:[0,0,0] op_sel_hi:[1,1,0]" : "+v"(acc) : "v"(vu), "v"(pu)); \
    else if ((vh) == 1 && (ph) == 0) asm("v_fma_mix_f32 %0, %1, %2, %0 op_sel:[1,0,0] op_sel_hi:[1,1,0]" : "+v"(acc) : "v"(vu), "v"(pu)); \
    else if ((vh) == 0 && (ph) == 1) asm("v_fma_mix_f32 %0, %1, %2, %0 op_sel:[0,1,0] op_sel_hi:[1,1,0]" : "+v"(acc) : "v"(vu), "v"(pu)); \
    else                             asm("v_fma_mix_f32 %0, %1, %2, %0 op_sel:[1,1,0] op_sel_hi:[1,1,0]" : "+v"(acc) : "v"(vu), "v"(pu)); \
} while (0)

// acc_pk(2xf16) += broadcast(half ph of pu) * vu(2xf16) — one v_pk_fma_f16.
// op_sel[0]/op_sel_hi[0] both select the SAME half of p -> hw broadcast, no dup op.
#define PKFMA(accu, vu, pu, ph) do {                                                                                \
    if ((ph) == 0) asm("v_pk_fma_f16 %0, %2, %1, %0 op_sel:[0,0,0] op_sel_hi:[0,1,1]" : "+v"(accu) : "v"(vu), "v"(pu)); \
    else           asm("v_pk_fma_f16 %0, %2, %1, %0 op_sel:[1,0,0] op_sel_hi:[1,1,1]" : "+v"(accu) : "v"(vu), "v"(pu)); \
} while (0)

// a32(f32) += f16 half of pk — one v_fma_mix_f32 with inline 1.0.
#define FLUSHLO(a32, pk) asm("v_fma_mix_f32 %0, 1.0, %1, %0 op_sel:[0,0,0] op_sel_hi:[0,1,0]" : "+v"(a32) : "v"(pk))
#define FLUSHHI(a32, pk) asm("v_fma_mix_f32 %0, 1.0, %1, %0 op_sel:[0,1,0] op_sel_hi:[0,1,0]" : "+v"(a32) : "v"(pk))

// ---------------------------------------------------------------------------
// Pack W (Ch x Cin) -> pair-interleaved f16 for v_dot2; resolve same_WqWk.
// ---------------------------------------------------------------------------
__global__ __launch_bounds__(256) void wtrans_kernel(
    const float* __restrict__ Wq, const float* __restrict__ Wk,
    const int* __restrict__ same_flag,
    uint* __restrict__ WtPQ, uint* __restrict__ WtPK)
{
    const float* Wsel = (same_flag[0] != 0) ? Wq : Wk;
    for (int idx = threadIdx.x; idx < (CIN / 2) * CH; idx += 256) {
        int i2 = idx >> 6;
        int o  = idx & 63;
        CV a; a.p = __builtin_amdgcn_cvt_pkrtz(Wq[o * CIN + 2 * i2], Wq[o * CIN + 2 * i2 + 1]);
        WtPQ[idx] = a.u;
        CV b2; b2.p = __builtin_amdgcn_cvt_pkrtz(Wsel[o * CIN + 2 * i2], Wsel[o * CIN + 2 * i2 + 1]);
        WtPK[idx] = b2.u;
    }
}

// ---------------------------------------------------------------------------
// conv3 (round-6 structure, unroll 8 for deeper load pipelining): three 1x1
// convs (blockIdx.y = 0:Q(left) 1:K(left) 2:K(right)), v_dot2_f32_f16,
// (256,4) keeps high TLP for the latency-bound strided loads.
// ---------------------------------------------------------------------------
__global__ __launch_bounds__(256, 4) void conv3_kernel(
    const float* __restrict__ left, const float* __restrict__ right,
    const uint* __restrict__ WtPQ, const uint* __restrict__ WtPK,
    const float* __restrict__ bq, const float* __restrict__ bk,
    const int* __restrict__ same_flag,
    uint* __restrict__ dQ, uint* __restrict__ dKL, uint* __restrict__ dKR)
{
    int which = blockIdx.y;
    const float* x    = (which == 2) ? right : left;
    const uint*  Wt   = (which == 0) ? WtPQ : WtPK;
    const float* bias = (which == 0 || same_flag[0] != 0) ? bq : bk;
    uint* dst         = (which == 0) ? dQ : ((which == 1) ? dKL : dKR);

    int b  = blockIdx.x >> 2;
    int px = ((blockIdx.x & 3) << 8) + threadIdx.x;
    const float* xb = x + (size_t)b * (CIN * NPX) + px;

    float acc[CH];
#pragma unroll
    for (int o = 0; o < CH; ++o) acc[o] = bias[o];

#pragma unroll 8
    for (int i2 = 0; i2 < CIN / 2; ++i2) {
        float x0 = xb[(size_t)(2 * i2) << 10];
        float x1 = xb[(size_t)(2 * i2 + 1) << 10];
        CV xp; xp.p = __builtin_amdgcn_cvt_pkrtz(x0, x1);
        const uint* wrow = Wt + (i2 << 6);
#pragma unroll
        for (int o = 0; o < CH; ++o) {
            CV wv; wv.u = wrow[o];
            acc[o] = FDOT2(xp.h, wv.h, acc[o]);
        }
    }

    uint* db = dst + (size_t)b * ((CH / 2) * NPX) + px;
#pragma unroll
    for (int o2 = 0; o2 < CH / 2; ++o2) {
        CV cv; cv.p = __builtin_amdgcn_cvt_pkrtz(acc[2 * o2], acc[2 * o2 + 1]);
        db[(size_t)o2 << 10] = cv.u;
    }
}

// ---------------------------------------------------------------------------
// attend2 (round-10 base): 16-row tile, 2 vertical px/thread, shared taps.
// Phase C changes this round: v_pk_fma_f16 (2 ch-MACs/instr, op_sel p
// broadcast) with f32 flush every 2 dh rows (<=14-tap f16 partials), and a
// true double-buffer rotation -> ONE barrier per V group (was 2).
// ---------------------------------------------------------------------------
__global__ __launch_bounds__(256) __attribute__((amdgpu_waves_per_eu(2, 2)))
void attend2_kernel(
    const uint* __restrict__ Q, const uint* __restrict__ KR,
    const uint* __restrict__ KL,
    const float* __restrict__ right, const float* __restrict__ left,
    float* __restrict__ out, const int* __restrict__ self_flag)
{
    __shared__ __align__(16) uint buf[2 * BUFU];   // 28160 B

    int side = blockIdx.y;            // 0: right-attend, 1: left-attend
    int b    = blockIdx.x >> 1;
    int h0   = (blockIdx.x & 1) << 4;
    int t    = threadIdx.x;
    int w    = t & 31;
    int r2   = (t >> 5) << 1;         // 0,2,..,14
    int h    = h0 + r2;               // rows h and h+1
    int qoff = (h << 5) + w;
    int cb   = side ? 0 : CIN;

    const uint*  K = side ? KL : KR;
    const float* V = side ? left : right;

    if (side == 1 && self_flag[0] == 0) {
        const float* s = left + (size_t)b * (CIN * NPX) + qoff;
        float* d = out + (size_t)b * (2 * CIN * NPX) + qoff;
        for (int c = 0; c < CIN; ++c) {
            d[(size_t)c << 10] = s[(size_t)c << 10];
            d[((size_t)c << 10) + 32] = s[((size_t)c << 10) + 32];
        }
        return;
    }

    // ---- zero both buffers once (borders stay 0 through A and C) ----
#pragma unroll
    for (int i = 0; i < 7; ++i) {
        int idx = t + (i << 8);
        if (idx < 2 * BUFU / 4) ((int4*)buf)[idx] = int4{0, 0, 0, 0};
    }

    int rowlo = (h0 == 0) ? 0 : h0 - 3;   // first valid global row (19 staged)
    int rowof = (h0 == 0) ? 3 : 0;        // its LDS row
    int c2    = (t >> 5) & 3;             // staging channel-pair within group
    int rr    = t >> 7;                   // staging row parity

    const uint* Kb = K + (size_t)b * ((CH / 2) * NPX);
    const uint* Qb = Q + (size_t)b * ((CH / 2) * NPX);

    float sc0[NWIN], sc1[NWIN];
#pragma unroll
    for (int i = 0; i < NWIN; ++i) { sc0[i] = 0.f; sc1[i] = 0.f; }

#define ROWS_OK(i) (rr + 2 * (i) < 19)
#define PFK(g, arr)                                                            \
    _Pragma("unroll") for (int i = 0; i < 10; ++i) if (ROWS_OK(i))             \
        arr[i] = Kb[((size_t)((((g) << 2) + c2)) << 10) + ((rowlo + rr + 2 * i) << 5) + w];
#define WRK(bp, arr)                                                           \
    _Pragma("unroll") for (int i = 0; i < 10; ++i) if (ROWS_OK(i))             \
        (bp)[((rowof + rr + 2 * i) * TCOLS + (w + 4)) * CELLU + c2] = arr[i];

#define COMPA(bp, g) {                                                         \
    CV qa[4], qc[4];                                                           \
    _Pragma("unroll") for (int j = 0; j < 4; ++j) {                            \
        qa[j].u = Qb[((size_t)(((g) << 2) + j) << 10) + qoff];                 \
        qc[j].u = Qb[((size_t)(((g) << 2) + j) << 10) + qoff + 32];            \
    }                                                                          \
    _Pragma("unroll") for (int dh = 0; dh < 8; ++dh) {                         \
        int cu0 = ((r2 + dh) * TCOLS + (w + 1)) * CELLU;                       \
        _Pragma("unroll") for (int dw = 0; dw < 7; ++dw) {                     \
            U4 kk; kk.v = *(const int4*)((bp) + cu0 + dw * CELLU);             \
            if (dh < 7) {                                                      \
                float s = sc0[dh * 7 + dw];                                    \
                _Pragma("unroll") for (int j = 0; j < 4; ++j)                  \
                    s = FDOT2(kk.h[j], qa[j].h, s);                            \
                sc0[dh * 7 + dw] = s;                                          \
            }                                                                  \
            if (dh >= 1) {                                                     \
                float s = sc1[(dh - 1) * 7 + dw];                              \
                _Pragma("unroll") for (int j = 0; j < 4; ++j)                  \
                    s = FDOT2(kk.h[j], qc[j].h, s);                            \
                sc1[(dh - 1) * 7 + dw] = s;                                    \
            }                                                                  \
        }                                                                      \
    } }

    // ---- Phase A: 8 groups of 8 ch, processed in dbuf pairs ----
    {
        uint pfa[10], pfb[10];
        PFK(0, pfa); PFK(1, pfb);
#pragma unroll 1
        for (int gp = 0; gp < 4; ++gp) {
            __syncthreads();                 // prior compute / zero-fill done
            WRK(buf, pfa); WRK(buf + BUFU, pfb);
            if (gp < 3) { PFK(2 * gp + 2, pfa); PFK(2 * gp + 3, pfb); }
            __syncthreads();                 // staged data visible
            COMPA(buf, 2 * gp);
            COMPA(buf + BUFU, 2 * gp + 1);
        }
    }

    // ---- masked softmax per pixel; weights packed to f16 pairs ----
    uint ph0[25], ph1[25];
    {
        float m = NEG_INF_F;
#pragma unroll
        for (int dh = 0; dh < 7; ++dh)
#pragma unroll
            for (int dw = 0; dw < 7; ++dw) {
                int i = dh * 7 + dw;
                bool vld = ((unsigned)(h + dh - 3) < 32u) && ((unsigned)(w + dw - 3) < 32u);
                sc0[i] = vld ? sc0[i] : NEG_INF_F;
                m = fmaxf(m, sc0[i]);
            }
        float ssum = 0.f;
#pragma unroll
        for (int i = 0; i < NWIN; ++i) { sc0[i] = __expf(sc0[i] - m); ssum += sc0[i]; }
        float inv = 1.f / ssum;
#pragma unroll
        for (int j = 0; j < 24; ++j) {
            CV cv; cv.p = __builtin_amdgcn_cvt_pkrtz(sc0[2 * j] * inv, sc0[2 * j + 1] * inv);
            ph0[j] = cv.u;
        }
        CV cv; cv.p = __builtin_amdgcn_cvt_pkrtz(sc0[48] * inv, 0.f);
        ph0[24] = cv.u;
    }
    {
        float m = NEG_INF_F;
#pragma unroll
        for (int dh = 0; dh < 7; ++dh)
#pragma unroll
            for (int dw = 0; dw < 7; ++dw) {
                int i = dh * 7 + dw;
                bool vld = ((unsigned)(h + 1 + dh - 3) < 32u) && ((unsigned)(w + dw - 3) < 32u);
                sc1[i] = vld ? sc1[i] : NEG_INF_F;
                m = fmaxf(m, sc1[i]);
            }
        float ssum = 0.f;
#pragma unroll
        for (int i = 0; i < NWIN; ++i) { sc1[i] = __expf(sc1[i] - m); ssum += sc1[i]; }
        float inv = 1.f / ssum;
#pragma unroll
        for (int j = 0; j < 24; ++j) {
            CV cv; cv.p = __builtin_amdgcn_cvt_pkrtz(sc1[2 * j] * inv, sc1[2 * j + 1] * inv);
            ph1[j] = cv.u;
        }
        CV cv; cv.p = __builtin_amdgcn_cvt_pkrtz(sc1[48] * inv, 0.f);
        ph1[24] = cv.u;
    }

    // ---- Phase C: 16 groups of 8 ch, pk_fma + f32 flush, 1 barrier/group ----
    const float* Vb = V + (size_t)b * (CIN * NPX);
    float* ob = out + (size_t)b * (2 * CIN * NPX) + ((size_t)cb << 10) + qoff;

    float pv0[10], pv1[10];
#define PFV(vg) {                                                              \
    const float* va = Vb + ((size_t)((((vg) << 2) + c2) * 2) << 10);           \
    const float* vc = va + NPX;                                                \
    _Pragma("unroll") for (int i = 0; i < 10; ++i) if (ROWS_OK(i)) {           \
        int gi = ((rowlo + rr + 2 * i) << 5) + w;                              \
        pv0[i] = va[gi]; pv1[i] = vc[gi];                                      \
    } }
#define WRV(bp)                                                                \
    _Pragma("unroll") for (int i = 0; i < 10; ++i) if (ROWS_OK(i)) {           \
        CV cv; cv.p = __builtin_amdgcn_cvt_pkrtz(pv0[i], pv1[i]);              \
        (bp)[((rowof + rr + 2 * i) * TCOLS + (w + 4)) * CELLU + c2] = cv.u;    \
    }

    PFV(0);
    __syncthreads();                     // phase-A reads of both buffers done
    WRV(buf);                            // group 0 -> buf0

#pragma unroll 1
    for (int vg = 0; vg < 16; ++vg) {
        if (vg < 15) PFV(vg + 1);        // issue next group's loads early
        __syncthreads();                 // current group's writes visible

        const uint* bp = buf + (vg & 1) * BUFU;
        float a0[8], a1[8];
#pragma unroll
        for (int c = 0; c < 8; ++c) { a0[c] = 0.f; a1[c] = 0.f; }
        uint pk0[4], pk1[4];
#pragma unroll
        for (int j = 0; j < 4; ++j) { pk0[j] = 0u; pk1[j] = 0u; }

#pragma unroll
        for (int dh = 0; dh < 8; ++dh) {
            int cu0 = ((r2 + dh) * TCOLS + (w + 1)) * CELLU;
#pragma unroll
            for (int dw = 0; dw < 7; ++dw) {
                U4 kk; kk.v = *(const int4*)(bp + cu0 + dw * CELLU);
                if (dh < 7) {
                    int tp = dh * 7 + dw;
#pragma unroll
                    for (int j = 0; j < 4; ++j)
                        PKFMA(pk0[j], kk.u[j], ph0[tp >> 1], (tp & 1));
                }
                if (dh >= 1) {
                    int tp = (dh - 1) * 7 + dw;
#pragma unroll
                    for (int j = 0; j < 4; ++j)
                        PKFMA(pk1[j], kk.u[j], ph1[tp >> 1], (tp & 1));
                }
            }
            if (dh & 1) {                // flush f16 partials every 2 dh rows
#pragma unroll
                for (int j = 0; j < 4; ++j) {
                    FLUSHLO(a0[2 * j], pk0[j]); FLUSHHI(a0[2 * j + 1], pk0[j]); pk0[j] = 0u;
                    FLUSHLO(a1[2 * j], pk1[j]); FLUSHHI(a1[2 * j + 1], pk1[j]); pk1[j] = 0u;
                }
            }
        }

        if (vg < 15) WRV(buf + ((vg + 1) & 1) * BUFU);   // stage next group

#pragma unroll
        for (int c = 0; c < 8; ++c) {
            ob[((size_t)((vg << 3) + c)) << 10] = a0[c];
            ob[(((size_t)((vg << 3) + c)) << 10) + 32] = a1[c];
        }
    }
}

// ---------------------------------------------------------------------------
// 3 launches: wtrans -> conv3 (3072 blocks) -> attend2 (1024 blocks).
// ws: 3 x 32 MiB pair-packed f16 (Q, K_left, K_right) + 2 packed W = 96.03 MiB.
// ---------------------------------------------------------------------------
extern "C" void kernel_launch(void* const* d_in, const int* in_sizes, int n_in,
                              void* d_out, int out_size, void* d_ws, size_t ws_size,
                              hipStream_t stream)
{
    (void)in_sizes; (void)n_in; (void)out_size; (void)ws_size;

    const float* left  = (const float*)d_in[0];
    const float* right = (const float*)d_in[1];
    const float* Wq    = (const float*)d_in[2];
    const float* bq    = (const float*)d_in[3];
    const float* Wk    = (const float*)d_in[4];
    const float* bk    = (const float*)d_in[5];
    const int* self_flag = (const int*)d_in[7];
    const int* same_flag = (const int*)d_in[8];

    uint* wsQ  = (uint*)d_ws;                              // 32 MiB
    uint* wsKL = wsQ  + (size_t)B_ * (CH / 2) * NPX;       // 32 MiB
    uint* wsKR = wsKL + (size_t)B_ * (CH / 2) * NPX;       // 32 MiB
    uint* WtPQ = wsKR + (size_t)B_ * (CH / 2) * NPX;       // 4096 uints
    uint* WtPK = WtPQ + (CIN / 2) * CH;

    float* out = (float*)d_out;

    wtrans_kernel<<<1, 256, 0, stream>>>(Wq, Wk, same_flag, WtPQ, WtPK);

    conv3_kernel<<<dim3(B_ * 4, 3), 256, 0, stream>>>(
        left, right, WtPQ, WtPK, bq, bk, same_flag, wsQ, wsKL, wsKR);

    attend2_kernel<<<dim3(B_ * 2, 2), 256, 0, stream>>>(
        wsQ, wsKR, wsKL, right, left, out, self_flag);
}

// Round 12
// 267.321 us; speedup vs baseline: 4.1511x; 1.1176x over previous
//
#include <hip/hip_runtime.h>
#include <hip/hip_fp16.h>

#define B_    256
#define CIN   128
#define CH    64
#define NPX   1024   // 32*32
#define NWIN  49
#define TROWS 22     // 16 tile rows + 3 halo each side
#define TCOLS 40     // 32 cols + 4 halo each side
#define CELLU 4      // uints per cell = 8 f16 channels = 16 B (benign 8-way banking)
#define BUFU  (TROWS * TCOLS * CELLU)   // 3520 uints = 14080 B per buffer
#define NEG_INF_F (-1e30f)

typedef _Float16 h2v __attribute__((ext_vector_type(2)));
typedef __fp16   p2v __attribute__((ext_vector_type(2)));   // cvt_pkrtz result type
typedef __fp16   p8v __attribute__((ext_vector_type(8)));   // mfma f16 operand type
typedef float    f4v __attribute__((ext_vector_type(4)));   // mfma acc type

#define FDOT2(a, b, c) __builtin_amdgcn_fdot2((a), (b), (c), false)

union CV { p2v p; h2v h; uint u; };
union U4 { int4 v; uint u[4]; h2v h[4]; };
union AF { uint4 u4; p8v h8; };

// acc(f32) += f16 half of vu * f16 half of pu — one v_fma_mix_f32.
#define FMIX(acc, vu, vh, pu, ph) do {                                                                              \
    if      ((vh) == 0 && (ph) == 0) asm("v_fma_mix_f32 %0, %1, %2, %0 op_sel:[0,0,0] op_sel_hi:[1,1,0]" : "+v"(acc) : "v"(vu), "v"(pu)); \
    else if ((vh) == 1 && (ph) == 0) asm("v_fma_mix_f32 %0, %1, %2, %0 op_sel:[1,0,0] op_sel_hi:[1,1,0]" : "+v"(acc) : "v"(vu), "v"(pu)); \
    else if ((vh) == 0 && (ph) == 1) asm("v_fma_mix_f32 %0, %1, %2, %0 op_sel:[0,1,0] op_sel_hi:[1,1,0]" : "+v"(acc) : "v"(vu), "v"(pu)); \
    else                             asm("v_fma_mix_f32 %0, %1, %2, %0 op_sel:[1,1,0] op_sel_hi:[1,1,0]" : "+v"(acc) : "v"(vu), "v"(pu)); \
} while (0)

// acc_pk(2xf16) += broadcast(half ph of pu) * vu(2xf16) — one v_pk_fma_f16.
#define PKFMA(accu, vu, pu, ph) do {                                                                                \
    if ((ph) == 0) asm("v_pk_fma_f16 %0, %2, %1, %0 op_sel:[0,0,0] op_sel_hi:[0,1,1]" : "+v"(accu) : "v"(vu), "v"(pu)); \
    else           asm("v_pk_fma_f16 %0, %2, %1, %0 op_sel:[1,0,0] op_sel_hi:[1,1,1]" : "+v"(accu) : "v"(vu), "v"(pu)); \
} while (0)

// a32(f32) += f16 half of pk — one v_fma_mix_f32 with inline 1.0.
#define FLUSHLO(a32, pk) asm("v_fma_mix_f32 %0, 1.0, %1, %0 op_sel:[0,0,0] op_sel_hi:[0,1,0]" : "+v"(a32) : "v"(pk))
#define FLUSHHI(a32, pk) asm("v_fma_mix_f32 %0, 1.0, %1, %0 op_sel:[0,1,0] op_sel_hi:[0,1,0]" : "+v"(a32) : "v"(pk))

// ---------------------------------------------------------------------------
// Pack W (Ch x Cin) into the EXACT A-fragment layout of mfma_f32_16x16x32_f16:
// WA[((mt*4+ks)*64 + lane)*4 + j] = pack(W[mt*16+(lane&15)][ks*32+(lane>>4)*8+2j],
//                                        W[  same row     ][     same k + 1  ])
// Any k-permutation misassumption cancels (B loads use the same mapping).
// ---------------------------------------------------------------------------
__global__ __launch_bounds__(256) void wtrans_kernel(
    const float* __restrict__ Wq, const float* __restrict__ Wk,
    const int* __restrict__ same_flag,
    uint* __restrict__ WAQ, uint* __restrict__ WAK)
{
    const float* Wsel = (same_flag[0] != 0) ? Wq : Wk;
    for (int idx = threadIdx.x; idx < 4096; idx += 256) {
        int j  = idx & 3;
        int l  = (idx >> 2) & 63;
        int ks = (idx >> 8) & 3;
        int mt = idx >> 10;
        int row = mt * 16 + (l & 15);
        int k0  = ks * 32 + ((l >> 4) << 3) + 2 * j;
        CV a; a.p = __builtin_amdgcn_cvt_pkrtz(Wq[row * CIN + k0], Wq[row * CIN + k0 + 1]);
        WAQ[idx] = a.u;
        CV b2; b2.p = __builtin_amdgcn_cvt_pkrtz(Wsel[row * CIN + k0], Wsel[row * CIN + k0 + 1]);
        WAK[idx] = b2.u;
    }
}

// ---------------------------------------------------------------------------
// MFMA conv: per wave, 16 px. B-frag = x[128ch x 16px] (32 f32 loads -> f16
// pairs). y=0: left -> Q AND K_left (B-frags reused, left fetched once).
// y=1: right -> K_right. Bias rides in as the MFMA C operand.
// D layout (m89): col=lane&15=px, row=(lane>>4)*4+reg -> pair-packed stores.
// ---------------------------------------------------------------------------
__global__ __launch_bounds__(256) void convm_kernel(
    const float* __restrict__ left, const float* __restrict__ right,
    const uint* __restrict__ WAQ, const uint* __restrict__ WAK,
    const float* __restrict__ bq, const float* __restrict__ bk,
    const int* __restrict__ same_flag,
    uint* __restrict__ dQ, uint* __restrict__ dKL, uint* __restrict__ dKR)
{
    int t   = threadIdx.x;
    int l   = t & 63;
    int wv  = t >> 6;
    int img = blockIdx.x >> 4;
    int px  = ((blockIdx.x & 15) << 6) + (wv << 4) + (l & 15);
    int che = (l >> 4) << 3;               // k-group base channel offset
    int r0  = (l >> 4) << 2;               // C row base within tile
    const float* biasK = (same_flag[0] != 0) ? bq : bk;

    const float* xb = ((blockIdx.y == 0) ? left : right) + (size_t)img * (CIN * NPX);

    // B fragments: 4 k-steps x 8 f16 (pack two f32 per uint)
    AF bf[4];
#pragma unroll
    for (int ks = 0; ks < 4; ++ks) {
        uint bu[4];
#pragma unroll
        for (int j = 0; j < 4; ++j) {
            int ch = ks * 32 + che + 2 * j;
            float x0 = xb[((size_t)ch << 10) + px];
            float x1 = xb[((size_t)(ch + 1) << 10) + px];
            CV c; c.p = __builtin_amdgcn_cvt_pkrtz(x0, x1);
            bu[j] = c.u;
        }
        bf[ks].u4 = make_uint4(bu[0], bu[1], bu[2], bu[3]);
    }

#define DOGEMM(WA, BIAS, DST)                                                   \
    {                                                                           \
      uint* dst = DST + (size_t)img * ((CH / 2) * NPX);                         \
      _Pragma("unroll") for (int mt = 0; mt < 4; ++mt) {                        \
        float4 bb = *(const float4*)((BIAS) + mt * 16 + r0);                    \
        f4v acc = { bb.x, bb.y, bb.z, bb.w };                                   \
        _Pragma("unroll") for (int ks = 0; ks < 4; ++ks) {                      \
            AF wa; wa.u4 = *(const uint4*)((WA) + (((mt << 2) + ks) << 8) + (l << 2)); \
            acc = __builtin_amdgcn_mfma_f32_16x16x32_f16(wa.h8, bf[ks].h8, acc, 0, 0, 0); \
        }                                                                       \
        int cp = (mt << 3) + ((l >> 4) << 1);                                   \
        CV c0; c0.p = __builtin_amdgcn_cvt_pkrtz(acc[0], acc[1]);               \
        dst[((size_t)cp << 10) + px] = c0.u;                                    \
        CV c1; c1.p = __builtin_amdgcn_cvt_pkrtz(acc[2], acc[3]);               \
        dst[((size_t)(cp + 1) << 10) + px] = c1.u;                              \
      }                                                                         \
    }

    if (blockIdx.y == 0) {
        DOGEMM(WAQ, bq,    dQ)
        DOGEMM(WAK, biasK, dKL)
    } else {
        DOGEMM(WAK, biasK, dKR)
    }
#undef DOGEMM
}

// ---------------------------------------------------------------------------
// attend2: UNCHANGED from round 11 (167 us measured). 16-row tile, 2 vertical
// px/thread, shared taps; phase C pk_fma + f32 flush, 1 barrier/group.
// ---------------------------------------------------------------------------
__global__ __launch_bounds__(256) __attribute__((amdgpu_waves_per_eu(2, 2)))
void attend2_kernel(
    const uint* __restrict__ Q, const uint* __restrict__ KR,
    const uint* __restrict__ KL,
    const float* __restrict__ right, const float* __restrict__ left,
    float* __restrict__ out, const int* __restrict__ self_flag)
{
    __shared__ __align__(16) uint buf[2 * BUFU];   // 28160 B

    int side = blockIdx.y;            // 0: right-attend, 1: left-attend
    int b    = blockIdx.x >> 1;
    int h0   = (blockIdx.x & 1) << 4;
    int t    = threadIdx.x;
    int w    = t & 31;
    int r2   = (t >> 5) << 1;         // 0,2,..,14
    int h    = h0 + r2;               // rows h and h+1
    int qoff = (h << 5) + w;
    int cb   = side ? 0 : CIN;

    const uint*  K = side ? KL : KR;
    const float* V = side ? left : right;

    if (side == 1 && self_flag[0] == 0) {
        const float* s = left + (size_t)b * (CIN * NPX) + qoff;
        float* d = out + (size_t)b * (2 * CIN * NPX) + qoff;
        for (int c = 0; c < CIN; ++c) {
            d[(size_t)c << 10] = s[(size_t)c << 10];
            d[((size_t)c << 10) + 32] = s[((size_t)c << 10) + 32];
        }
        return;
    }

    // ---- zero both buffers once (borders stay 0 through A and C) ----
#pragma unroll
    for (int i = 0; i < 7; ++i) {
        int idx = t + (i << 8);
        if (idx < 2 * BUFU / 4) ((int4*)buf)[idx] = int4{0, 0, 0, 0};
    }

    int rowlo = (h0 == 0) ? 0 : h0 - 3;   // first valid global row (19 staged)
    int rowof = (h0 == 0) ? 3 : 0;        // its LDS row
    int c2    = (t >> 5) & 3;             // staging channel-pair within group
    int rr    = t >> 7;                   // staging row parity

    const uint* Kb = K + (size_t)b * ((CH / 2) * NPX);
    const uint* Qb = Q + (size_t)b * ((CH / 2) * NPX);

    float sc0[NWIN], sc1[NWIN];
#pragma unroll
    for (int i = 0; i < NWIN; ++i) { sc0[i] = 0.f; sc1[i] = 0.f; }

#define ROWS_OK(i) (rr + 2 * (i) < 19)
#define PFK(g, arr)                                                            \
    _Pragma("unroll") for (int i = 0; i < 10; ++i) if (ROWS_OK(i))             \
        arr[i] = Kb[((size_t)((((g) << 2) + c2)) << 10) + ((rowlo + rr + 2 * i) << 5) + w];
#define WRK(bp, arr)                                                           \
    _Pragma("unroll") for (int i = 0; i < 10; ++i) if (ROWS_OK(i))             \
        (bp)[((rowof + rr + 2 * i) * TCOLS + (w + 4)) * CELLU + c2] = arr[i];

#define COMPA(bp, g) {                                                         \
    CV qa[4], qc[4];                                                           \
    _Pragma("unroll") for (int j = 0; j < 4; ++j) {                            \
        qa[j].u = Qb[((size_t)(((g) << 2) + j) << 10) + qoff];                 \
        qc[j].u = Qb[((size_t)(((g) << 2) + j) << 10) + qoff + 32];            \
    }                                                                          \
    _Pragma("unroll") for (int dh = 0; dh < 8; ++dh) {                         \
        int cu0 = ((r2 + dh) * TCOLS + (w + 1)) * CELLU;                       \
        _Pragma("unroll") for (int dw = 0; dw < 7; ++dw) {                     \
            U4 kk; kk.v = *(const int4*)((bp) + cu0 + dw * CELLU);             \
            if (dh < 7) {                                                      \
                float s = sc0[dh * 7 + dw];                                    \
                _Pragma("unroll") for (int j = 0; j < 4; ++j)                  \
                    s = FDOT2(kk.h[j], qa[j].h, s);                            \
                sc0[dh * 7 + dw] = s;                                          \
            }                                                                  \
            if (dh >= 1) {                                                     \
                float s = sc1[(dh - 1) * 7 + dw];                              \
                _Pragma("unroll") for (int j = 0; j < 4; ++j)                  \
                    s = FDOT2(kk.h[j], qc[j].h, s);                            \
                sc1[(dh - 1) * 7 + dw] = s;                                    \
            }                                                                  \
        }                                                                      \
    } }

    // ---- Phase A: 8 groups of 8 ch, processed in dbuf pairs ----
    {
        uint pfa[10], pfb[10];
        PFK(0, pfa); PFK(1, pfb);
#pragma unroll 1
        for (int gp = 0; gp < 4; ++gp) {
            __syncthreads();                 // prior compute / zero-fill done
            WRK(buf, pfa); WRK(buf + BUFU, pfb);
            if (gp < 3) { PFK(2 * gp + 2, pfa); PFK(2 * gp + 3, pfb); }
            __syncthreads();                 // staged data visible
            COMPA(buf, 2 * gp);
            COMPA(buf + BUFU, 2 * gp + 1);
        }
    }

    // ---- masked softmax per pixel; weights packed to f16 pairs ----
    uint ph0[25], ph1[25];
    {
        float m = NEG_INF_F;
#pragma unroll
        for (int dh = 0; dh < 7; ++dh)
#pragma unroll
            for (int dw = 0; dw < 7; ++dw) {
                int i = dh * 7 + dw;
                bool vld = ((unsigned)(h + dh - 3) < 32u) && ((unsigned)(w + dw - 3) < 32u);
                sc0[i] = vld ? sc0[i] : NEG_INF_F;
                m = fmaxf(m, sc0[i]);
            }
        float ssum = 0.f;
#pragma unroll
        for (int i = 0; i < NWIN; ++i) { sc0[i] = __expf(sc0[i] - m); ssum += sc0[i]; }
        float inv = 1.f / ssum;
#pragma unroll
        for (int j = 0; j < 24; ++j) {
            CV cv; cv.p = __builtin_amdgcn_cvt_pkrtz(sc0[2 * j] * inv, sc0[2 * j + 1] * inv);
            ph0[j] = cv.u;
        }
        CV cv; cv.p = __builtin_amdgcn_cvt_pkrtz(sc0[48] * inv, 0.f);
        ph0[24] = cv.u;
    }
    {
        float m = NEG_INF_F;
#pragma unroll
        for (int dh = 0; dh < 7; ++dh)
#pragma unroll
            for (int dw = 0; dw < 7; ++dw) {
                int i = dh * 7 + dw;
                bool vld = ((unsigned)(h + 1 + dh - 3) < 32u) && ((unsigned)(w + dw - 3) < 32u);
                sc1[i] = vld ? sc1[i] : NEG_INF_F;
                m = fmaxf(m, sc1[i]);
            }
        float ssum = 0.f;
#pragma unroll
        for (int i = 0; i < NWIN; ++i) { sc1[i] = __expf(sc1[i] - m); ssum += sc1[i]; }
        float inv = 1.f / ssum;
#pragma unroll
        for (int j = 0; j < 24; ++j) {
            CV cv; cv.p = __builtin_amdgcn_cvt_pkrtz(sc1[2 * j] * inv, sc1[2 * j + 1] * inv);
            ph1[j] = cv.u;
        }
        CV cv; cv.p = __builtin_amdgcn_cvt_pkrtz(sc1[48] * inv, 0.f);
        ph1[24] = cv.u;
    }

    // ---- Phase C: 16 groups of 8 ch, pk_fma + f32 flush, 1 barrier/group ----
    const float* Vb = V + (size_t)b * (CIN * NPX);
    float* ob = out + (size_t)b * (2 * CIN * NPX) + ((size_t)cb << 10) + qoff;

    float pv0[10], pv1[10];
#define PFV(vg) {                                                              \
    const float* va = Vb + ((size_t)((((vg) << 2) + c2) * 2) << 10);           \
    const float* vc = va + NPX;                                                \
    _Pragma("unroll") for (int i = 0; i < 10; ++i) if (ROWS_OK(i)) {           \
        int gi = ((rowlo + rr + 2 * i) << 5) + w;                              \
        pv0[i] = va[gi]; pv1[i] = vc[gi];                                      \
    } }
#define WRV(bp)                                                                \
    _Pragma("unroll") for (int i = 0; i < 10; ++i) if (ROWS_OK(i)) {           \
        CV cv; cv.p = __builtin_amdgcn_cvt_pkrtz(pv0[i], pv1[i]);              \
        (bp)[((rowof + rr + 2 * i) * TCOLS + (w + 4)) * CELLU + c2] = cv.u;    \
    }

    PFV(0);
    __syncthreads();                     // phase-A reads of both buffers done
    WRV(buf);                            // group 0 -> buf0

#pragma unroll 1
    for (int vg = 0; vg < 16; ++vg) {
        if (vg < 15) PFV(vg + 1);        // issue next group's loads early
        __syncthreads();                 // current group's writes visible

        const uint* bp = buf + (vg & 1) * BUFU;
        float a0[8], a1[8];
#pragma unroll
        for (int c = 0; c < 8; ++c) { a0[c] = 0.f; a1[c] = 0.f; }
        uint pk0[4], pk1[4];
#pragma unroll
        for (int j = 0; j < 4; ++j) { pk0[j] = 0u; pk1[j] = 0u; }

#pragma unroll
        for (int dh = 0; dh < 8; ++dh) {
            int cu0 = ((r2 + dh) * TCOLS + (w + 1)) * CELLU;
#pragma unroll
            for (int dw = 0; dw < 7; ++dw) {
                U4 kk; kk.v = *(const int4*)(bp + cu0 + dw * CELLU);
                if (dh < 7) {
                    int tp = dh * 7 + dw;
#pragma unroll
                    for (int j = 0; j < 4; ++j)
                        PKFMA(pk0[j], kk.u[j], ph0[tp >> 1], (tp & 1));
                }
                if (dh >= 1) {
                    int tp = (dh - 1) * 7 + dw;
#pragma unroll
                    for (int j = 0; j < 4; ++j)
                        PKFMA(pk1[j], kk.u[j], ph1[tp >> 1], (tp & 1));
                }
            }
            if (dh & 1) {                // flush f16 partials every 2 dh rows
#pragma unroll
                for (int j = 0; j < 4; ++j) {
                    FLUSHLO(a0[2 * j], pk0[j]); FLUSHHI(a0[2 * j + 1], pk0[j]); pk0[j] = 0u;
                    FLUSHLO(a1[2 * j], pk1[j]); FLUSHHI(a1[2 * j + 1], pk1[j]); pk1[j] = 0u;
                }
            }
        }

        if (vg < 15) WRV(buf + ((vg + 1) & 1) * BUFU);   // stage next group

#pragma unroll
        for (int c = 0; c < 8; ++c) {
            ob[((size_t)((vg << 3) + c)) << 10] = a0[c];
            ob[(((size_t)((vg << 3) + c)) << 10) + 32] = a1[c];
        }
    }
}

// ---------------------------------------------------------------------------
// 3 launches: wtrans -> convm (8192 blocks) -> attend2 (1024 blocks).
// ws: 3 x 32 MiB pair-packed f16 (Q, K_left, K_right) + 2 A-frag W = 96.03 MiB.
// ---------------------------------------------------------------------------
extern "C" void kernel_launch(void* const* d_in, const int* in_sizes, int n_in,
                              void* d_out, int out_size, void* d_ws, size_t ws_size,
                              hipStream_t stream)
{
    (void)in_sizes; (void)n_in; (void)out_size; (void)ws_size;

    const float* left  = (const float*)d_in[0];
    const float* right = (const float*)d_in[1];
    const float* Wq    = (const float*)d_in[2];
    const float* bq    = (const float*)d_in[3];
    const float* Wk    = (const float*)d_in[4];
    const float* bk    = (const float*)d_in[5];
    const int* self_flag = (const int*)d_in[7];
    const int* same_flag = (const int*)d_in[8];

    uint* wsQ  = (uint*)d_ws;                              // 32 MiB
    uint* wsKL = wsQ  + (size_t)B_ * (CH / 2) * NPX;       // 32 MiB
    uint* wsKR = wsKL + (size_t)B_ * (CH / 2) * NPX;       // 32 MiB
    uint* WAQ  = wsKR + (size_t)B_ * (CH / 2) * NPX;       // 4096 uints
    uint* WAK  = WAQ + 4096;

    float* out = (float*)d_out;

    wtrans_kernel<<<1, 256, 0, stream>>>(Wq, Wk, same_flag, WAQ, WAK);

    convm_kernel<<<dim3(B_ * 16, 2), 256, 0, stream>>>(
        left, right, WAQ, WAK, bq, bk, same_flag, wsQ, wsKL, wsKR);

    attend2_kernel<<<dim3(B_ * 2, 2), 256, 0, stream>>>(
        wsQ, wsKR, wsKL, right, left, out, self_flag);
}